// Round 5
// baseline (404.403 us; speedup 1.0000x reference)
//
#include <hip/hip_runtime.h>

#define B_SZ   16
#define P_IN   6400
#define H_IN   80
#define OUTHW  160
#define NCLASS 8

typedef __attribute__((ext_vector_type(8))) short  short8v;
typedef __attribute__((ext_vector_type(4))) float  f32x4;
typedef __attribute__((ext_vector_type(4))) unsigned short ushort4v;

__device__ __forceinline__ unsigned short f2bf(float x) {
    union { float f; unsigned int u; } v; v.f = x;
    unsigned int r = v.u + 0x7fffu + ((v.u >> 16) & 1u);   // RNE
    return (unsigned short)(r >> 16);
}
__device__ __forceinline__ float bf2f(unsigned short h) {
    union { unsigned int u; float f; } v; v.u = ((unsigned int)h) << 16;
    return v.f;
}

__device__ __forceinline__ void gload16(const void* g, void* lds) {
    __builtin_amdgcn_global_load_lds(
        (const __attribute__((address_space(1))) unsigned int*)g,
        (__attribute__((address_space(3))) unsigned int*)lds, 16, 0, 0);
}

// ---------- fused weight prep: fp32 -> bf16 hi/lo ----------
__global__ void wprep3(const float* __restrict__ w1, const float* __restrict__ w2,
                       const float* __restrict__ w3,
                       unsigned short* __restrict__ h1, unsigned short* __restrict__ l1,
                       unsigned short* __restrict__ h2, unsigned short* __restrict__ l2,
                       unsigned short* __restrict__ h3, unsigned short* __restrict__ l3)
{
    int i = blockIdx.x * 256 + threadIdx.x;
    const float* src; unsigned short *h, *l; int off;
    if (i < 131072)      { src = w1; h = h1; l = l1; off = i; }
    else if (i < 262144) { src = w2; h = h2; l = l2; off = i - 131072; }
    else                 { src = w3; h = h3; l = l3; off = i - 262144;
                           if (off >= 32768) return; }
    float v = src[off];
    unsigned short hi = f2bf(v);
    h[off] = hi;
    l[off] = f2bf(v - bf2f(hi));
}

// ---------- conv1: fused f32-feature -> MFMA. Y[b][n][m] = relu(W X + b) ----------
// 128x128 tile, BK=32, NK=8. A = Wh/Wl bf16 via gload_lds (slot swizzle as R4).
// B = raw f32 feature tile [32k][128n] via gload_lds, 64B-parity XOR swizzle
// (pre-swizzled global source; read applies idx ^= (kg&1)<<4). Fragment build:
// 8x ds_read_b32 + RNE pack (bit-identical to old fprep). Counted-vmcnt 2-barrier.
__global__ __launch_bounds__(256, 2)
void conv1_fused(const unsigned short* __restrict__ Wh, const unsigned short* __restrict__ Wl,
                 const float* __restrict__ bias,
                 const float* __restrict__ F,          // [b][256][6400] f32
                 unsigned short* __restrict__ Y)       // [b][6400][512] bf16
{
    constexpr int K = 256, NK = 8, NM = 4, M = 512;
    __shared__ unsigned short As_h[2][4096], As_l[2][4096];
    __shared__ float Bf[2][4096];                      // [32][128] f32, 16KB each
    const int tid = threadIdx.x, lane = tid & 63, w = tid >> 6;
    const int wm = w >> 1, wn = w & 1;

    const int nb = gridDim.x, id = blockIdx.x;
    const int wg = (id & 7) * (nb >> 3) + (id >> 3);
    const int bb  = wg / (50 * NM);
    const int rem = wg - bb * (50 * NM);
    const int n0 = (rem / NM) * 128;
    const int m0 = (rem - (rem / NM) * NM) * NM == 0 ? (rem % NM) * 128 : (rem % NM) * 128;

    const size_t abase = (size_t)m0 * K;
    const size_t fbase = (size_t)bb * 256 * P_IN + n0;   // float index of tile origin

    f32x4 acc[4][4];
#pragma unroll
    for (int i = 0; i < 4; ++i)
#pragma unroll
        for (int j = 0; j < 4; ++j) acc[i][j] = (f32x4)0.f;

    // A staging (2 streams x 2 chunks of 1KB): row = ch*16+(lane>>2), slot = lane&3
    int a_row[2], a_k8[2], a_lo[2];
#pragma unroll
    for (int q = 0; q < 2; ++q) {
        const int ch = 2 * w + q;
        a_row[q] = ch * 16 + (lane >> 2);
        a_k8[q]  = ((((lane & 3) - (a_row[q] >> 1)) & 3) << 3);
        a_lo[q]  = ch * 512;
    }
    // B staging (4 x 1KB = 2 rows each): k = q*8 + w*2 + (lane>>5), in-row float = (lane&31)*4
    int b_k[4], b_src[4], b_lo[4];
#pragma unroll
    for (int q = 0; q < 4; ++q) {
        b_k[q]   = q * 8 + w * 2 + (lane >> 5);
        const int inrow = (lane & 31) * 4;
        b_src[q] = inrow ^ ((((b_k[q] >> 3) & 1)) << 4);   // pre-swizzled source (floats)
        b_lo[q]  = q * 1024 + w * 256 + lane * 4;          // linear dest (floats)
    }
    // A frag offsets (ushorts): row stride 32; slot = (gsel + (r>>1)) & 3
    const int gsel = lane >> 4;
    int off_a[4], bidx[4];
#pragma unroll
    for (int mi = 0; mi < 4; ++mi) {
        const int r = wm * 64 + mi * 16 + (lane & 15);
        off_a[mi] = r * 32 + (((gsel + (r >> 1)) & 3) << 3);
    }
    // B frag base indices (floats): (gsel*8)*128 + n_local, XOR parity on bit4
#pragma unroll
    for (int ni = 0; ni < 4; ++ni) {
        const int nl = wn * 64 + ni * 16 + (lane & 15);
        bidx[ni] = ((gsel * 8) * 128 + nl) ^ ((gsel & 1) << 4);
    }

#define STAGE1(buf, kt) do {                                                  \
    _Pragma("unroll")                                                         \
    for (int q = 0; q < 4; ++q) {                                             \
        const size_t gx = fbase + (size_t)((kt) * 32 + b_k[q]) * P_IN + b_src[q]; \
        gload16(F + gx, &Bf[buf][b_lo[q]]);                                   \
    }                                                                         \
    _Pragma("unroll")                                                         \
    for (int q = 0; q < 2; ++q) {                                             \
        const size_t gW = abase + (size_t)a_row[q] * K + (kt) * 32 + a_k8[q]; \
        gload16(Wh + gW, &As_h[buf][a_lo[q]]);                                \
        gload16(Wl + gW, &As_l[buf][a_lo[q]]);                                \
    }                                                                         \
} while (0)

    int cur = 0;
    STAGE1(0, 0);
    __syncthreads();

    for (int t = 0; t < NK; ++t) {
        if (t + 1 < NK) {
            STAGE1(cur ^ 1, t + 1);
            asm volatile("s_waitcnt vmcnt(8)" ::: "memory");  // STAGE(t) landed; t+1 in flight
        } else {
            asm volatile("s_waitcnt vmcnt(0)" ::: "memory");
        }
        __builtin_amdgcn_s_barrier();
        __builtin_amdgcn_sched_barrier(0);

        short8v ah[4], al[4], bv[4];
#pragma unroll
        for (int mi = 0; mi < 4; ++mi) {
            ah[mi] = *(const short8v*)&As_h[cur][off_a[mi]];
            al[mi] = *(const short8v*)&As_l[cur][off_a[mi]];
        }
#pragma unroll
        for (int ni = 0; ni < 4; ++ni) {
            union { short8v v; unsigned short u[8]; } pk;
#pragma unroll
            for (int j = 0; j < 8; ++j)
                pk.u[j] = f2bf(Bf[cur][bidx[ni] + j * 128]);
            bv[ni] = pk.v;
        }
#pragma unroll
        for (int mi = 0; mi < 4; ++mi)
#pragma unroll
            for (int ni = 0; ni < 4; ++ni) {
                acc[mi][ni] = __builtin_amdgcn_mfma_f32_16x16x32_bf16(ah[mi], bv[ni], acc[mi][ni], 0, 0, 0);
                acc[mi][ni] = __builtin_amdgcn_mfma_f32_16x16x32_bf16(al[mi], bv[ni], acc[mi][ni], 0, 0, 0);
            }
        asm volatile("s_waitcnt lgkmcnt(0)" ::: "memory");
        __builtin_amdgcn_sched_barrier(0);
        __builtin_amdgcn_s_barrier();   // all reads of buf[cur] done -> reusable
        cur ^= 1;
    }
#undef STAGE1

    const int lhi = lane >> 4;
#pragma unroll
    for (int mi = 0; mi < 4; ++mi) {
        const int m_base = m0 + wm * 64 + mi * 16 + lhi * 4;
        const float4 b4 = *(const float4*)&bias[m_base];
#pragma unroll
        for (int ni = 0; ni < 4; ++ni) {
            const int n = n0 + wn * 64 + ni * 16 + (lane & 15);
            const size_t o = ((size_t)bb * P_IN + n) * M + m_base;
            ushort4v u;
            u.x = f2bf(fmaxf(acc[mi][ni][0] + b4.x, 0.f));
            u.y = f2bf(fmaxf(acc[mi][ni][1] + b4.y, 0.f));
            u.z = f2bf(fmaxf(acc[mi][ni][2] + b4.z, 0.f));
            u.w = f2bf(fmaxf(acc[mi][ni][3] + b4.w, 0.f));
            *(ushort4v*)&Y[o] = u;
        }
    }
}

// ---------- conv2/conv3: bf16-in MFMA conv, counted-vmcnt 2-barrier pipeline ----------
template<int K, int NM>
__global__ __launch_bounds__(256, 3)
void conv_mfma(const unsigned short* __restrict__ Wh, const unsigned short* __restrict__ Wl,
               const float* __restrict__ bias,
               const unsigned short* __restrict__ X, unsigned short* __restrict__ Y)
{
    constexpr int M  = NM * 128;
    constexpr int NK = K / 32;
    __shared__ unsigned short As_h[2][4096], As_l[2][4096], Bs[2][4096];
    const int tid = threadIdx.x, lane = tid & 63, w = tid >> 6;
    const int wm = w >> 1, wn = w & 1;

    const int nb = gridDim.x, id = blockIdx.x;
    const int wg = (id & 7) * (nb >> 3) + (id >> 3);
    const int bb  = wg / (50 * NM);
    const int rem = wg - bb * (50 * NM);
    const int n0 = (rem / NM) * 128;
    const int m0 = (rem % NM) * 128;

    const size_t abase = (size_t)m0 * K;
    const size_t xbase = ((size_t)bb * P_IN + n0) * K;

    f32x4 acc[4][4];
#pragma unroll
    for (int i = 0; i < 4; ++i)
#pragma unroll
        for (int j = 0; j < 4; ++j) acc[i][j] = (f32x4)0.f;

    int s_row[2], s_k8[2], s_lo[2];
#pragma unroll
    for (int q = 0; q < 2; ++q) {
        const int ch = 2 * w + q;
        s_row[q] = ch * 16 + (lane >> 2);
        s_k8[q]  = ((((lane & 3) - (s_row[q] >> 1)) & 3) << 3);
        s_lo[q]  = ch * 512;
    }
    int off_a[4], off_b[4];
    const int gsel = lane >> 4;
#pragma unroll
    for (int mi = 0; mi < 4; ++mi) {
        const int r = wm * 64 + mi * 16 + (lane & 15);
        off_a[mi] = r * 32 + (((gsel + (r >> 1)) & 3) << 3);
    }
#pragma unroll
    for (int ni = 0; ni < 4; ++ni) {
        const int r = wn * 64 + ni * 16 + (lane & 15);
        off_b[ni] = r * 32 + (((gsel + (r >> 1)) & 3) << 3);
    }

#define STAGE(buf, kt) do {                                                   \
    _Pragma("unroll")                                                         \
    for (int q = 0; q < 2; ++q) {                                             \
        const size_t kof = (size_t)(kt) * 32 + s_k8[q];                       \
        const size_t gW  = abase + (size_t)s_row[q] * K + kof;                \
        const size_t gX  = xbase + (size_t)s_row[q] * K + kof;                \
        gload16(Wh + gW, &As_h[buf][s_lo[q]]);                                \
        gload16(Wl + gW, &As_l[buf][s_lo[q]]);                                \
        gload16(X  + gX, &Bs[buf][s_lo[q]]);                                  \
    }                                                                         \
} while (0)

    int cur = 0;
    STAGE(0, 0);
    __syncthreads();

    for (int t = 0; t < NK; ++t) {
        if (t + 1 < NK) {
            STAGE(cur ^ 1, t + 1);
            asm volatile("s_waitcnt vmcnt(6)" ::: "memory");  // STAGE(t) landed; t+1 in flight
        } else {
            asm volatile("s_waitcnt vmcnt(0)" ::: "memory");
        }
        __builtin_amdgcn_s_barrier();
        __builtin_amdgcn_sched_barrier(0);

        short8v ah[4], al[4], bv[4];
#pragma unroll
        for (int mi = 0; mi < 4; ++mi) {
            ah[mi] = *(const short8v*)&As_h[cur][off_a[mi]];
            al[mi] = *(const short8v*)&As_l[cur][off_a[mi]];
        }
#pragma unroll
        for (int ni = 0; ni < 4; ++ni)
            bv[ni] = *(const short8v*)&Bs[cur][off_b[ni]];
#pragma unroll
        for (int mi = 0; mi < 4; ++mi)
#pragma unroll
            for (int ni = 0; ni < 4; ++ni) {
                acc[mi][ni] = __builtin_amdgcn_mfma_f32_16x16x32_bf16(ah[mi], bv[ni], acc[mi][ni], 0, 0, 0);
                acc[mi][ni] = __builtin_amdgcn_mfma_f32_16x16x32_bf16(al[mi], bv[ni], acc[mi][ni], 0, 0, 0);
            }
        asm volatile("s_waitcnt lgkmcnt(0)" ::: "memory");
        __builtin_amdgcn_sched_barrier(0);
        __builtin_amdgcn_s_barrier();
        cur ^= 1;
    }
#undef STAGE

    const int lhi = lane >> 4;
#pragma unroll
    for (int mi = 0; mi < 4; ++mi) {
        const int m_base = m0 + wm * 64 + mi * 16 + lhi * 4;
        const float4 b4 = *(const float4*)&bias[m_base];
#pragma unroll
        for (int ni = 0; ni < 4; ++ni) {
            const int n = n0 + wn * 64 + ni * 16 + (lane & 15);
            const size_t o = ((size_t)bb * P_IN + n) * M + m_base;
            ushort4v u;
            u.x = f2bf(fmaxf(acc[mi][ni][0] + b4.x, 0.f));
            u.y = f2bf(fmaxf(acc[mi][ni][1] + b4.y, 0.f));
            u.z = f2bf(fmaxf(acc[mi][ni][2] + b4.z, 0.f));
            u.w = f2bf(fmaxf(acc[mi][ni][3] + b4.w, 0.f));
            *(ushort4v*)&Y[o] = u;
        }
    }
}

// ---------- label scatter: slab-owned LDS accumulation ----------
__global__ __launch_bounds__(256)
void label_scatter(const int* __restrict__ lbl, float* __restrict__ g,
                   float* __restrict__ counts)
{
    __shared__ float sg[NCLASS][8][80];
    __shared__ float hist[NCLASS];
    const int b = blockIdx.x, slab = blockIdx.y;
    const int tid = threadIdx.x;
    const int r0 = slab * 8;
    for (int i = tid; i < NCLASS * 8 * 80; i += 256) ((float*)sg)[i] = 0.f;
    if (tid < NCLASS) hist[tid] = 0.f;
    __syncthreads();

    const int ibase = 2 * r0 - 1;
    for (int idx = tid; idx < 18 * 160; idx += 256) {
        const int ir = idx / 160, j = idx - ir * 160;
        const int i = ibase + ir;
        if (i < 0 || i >= OUTHW) continue;
        const int k = lbl[(size_t)b * (OUTHW * OUTHW) + i * OUTHW + j];
        const int mi = i >> 1, mj = j >> 1;
        int y0, y1, x0, x1; float wy0, wy1, wx0, wx1;
        if (i & 1) { y0 = mi; y1 = (mi < H_IN - 1) ? mi + 1 : H_IN - 1; wy0 = 0.75f; wy1 = 0.25f; }
        else       { y0 = (mi > 0) ? mi - 1 : 0; y1 = mi;               wy0 = 0.25f; wy1 = 0.75f; }
        if (j & 1) { x0 = mj; x1 = (mj < H_IN - 1) ? mj + 1 : H_IN - 1; wx0 = 0.75f; wx1 = 0.25f; }
        else       { x0 = (mj > 0) ? mj - 1 : 0; x1 = mj;               wx0 = 0.25f; wx1 = 0.75f; }
        if (mi >= r0 && mi < r0 + 8) atomicAdd(&hist[k], 1.f);
        const int ry0 = y0 - r0, ry1 = y1 - r0;
        if (ry0 >= 0 && ry0 < 8) {
            atomicAdd(&sg[k][ry0][x0], wy0 * wx0);
            atomicAdd(&sg[k][ry0][x1], wy0 * wx1);
        }
        if (ry1 >= 0 && ry1 < 8) {
            atomicAdd(&sg[k][ry1][x0], wy1 * wx0);
            atomicAdd(&sg[k][ry1][x1], wy1 * wx1);
        }
    }
    __syncthreads();
    for (int i = tid; i < NCLASS * 8 * 80; i += 256) {
        const int k = i / 640, rem2 = i - k * 640;
        g[((size_t)b * NCLASS + k) * P_IN + r0 * 80 + rem2] = ((const float*)sg)[i];
    }
    if (tid < NCLASS) atomicAdd(&counts[b * NCLASS + tid], hist[tid]);
}

// ---------- pool ----------
__global__ __launch_bounds__(256)
void pool2(const unsigned short* __restrict__ f3, const float* __restrict__ g,
           float* __restrict__ pooled)
{
    __shared__ float sg[NCLASS][800];
    const int b = blockIdx.x, chunk = blockIdx.y;
    const int tid = threadIdx.x;
#pragma unroll
    for (int i = 0; i < 25; ++i) {
        int idx = i * 256 + tid;
        int k = idx / 800, p = idx - k * 800;
        sg[k][p] = g[((size_t)b * NCLASS + k) * P_IN + chunk * 800 + p];
    }
    __syncthreads();

    const int c  = tid & 127;
    const int kg = tid >> 7;
    float acc0 = 0.f, acc1 = 0.f, acc2 = 0.f, acc3 = 0.f;
    const unsigned short* fb = f3 + ((size_t)b * P_IN + chunk * 800) * 128 + c;
    for (int p = 0; p < 800; ++p) {
        const float fv = bf2f(fb[(size_t)p * 128]);
        acc0 = fmaf(fv, sg[kg * 4 + 0][p], acc0);
        acc1 = fmaf(fv, sg[kg * 4 + 1][p], acc1);
        acc2 = fmaf(fv, sg[kg * 4 + 2][p], acc2);
        acc3 = fmaf(fv, sg[kg * 4 + 3][p], acc3);
    }
    atomicAdd(&pooled[((size_t)b * NCLASS + kg * 4 + 0) * 128 + c], acc0);
    atomicAdd(&pooled[((size_t)b * NCLASS + kg * 4 + 1) * 128 + c], acc1);
    atomicAdd(&pooled[((size_t)b * NCLASS + kg * 4 + 2) * 128 + c], acc2);
    atomicAdd(&pooled[((size_t)b * NCLASS + kg * 4 + 3) * 128 + c], acc3);
}

__global__ void finalize(const float* __restrict__ pooled, const float* __restrict__ counts,
                         float* __restrict__ out)
{
    const int b = blockIdx.x;
#pragma unroll
    for (int i = threadIdx.x; i < NCLASS * 128; i += 256) {
        const int k = i >> 7;
        const float cnt = counts[b * NCLASS + k];
        out[(size_t)b * NCLASS * 128 + i] = pooled[(size_t)b * NCLASS * 128 + i] / (cnt + 1e-8f);
    }
    if (threadIdx.x < NCLASS)
        out[B_SZ * NCLASS * 128 + b * NCLASS + threadIdx.x] =
            (counts[b * NCLASS + threadIdx.x] > 0.f) ? 1.f : 0.f;
}

extern "C" void kernel_launch(void* const* d_in, const int* in_sizes, int n_in,
                              void* d_out, int out_size, void* d_ws, size_t ws_size,
                              hipStream_t stream)
{
    const float* feature = (const float*)d_in[0];
    const int*   lbl     = (const int*)d_in[1];
    const float* w1 = (const float*)d_in[2];
    const float* b1 = (const float*)d_in[3];
    const float* w2 = (const float*)d_in[4];
    const float* b2 = (const float*)d_in[5];
    const float* w3 = (const float*)d_in[6];
    const float* b3 = (const float*)d_in[7];
    float* out = (float*)d_out;

    char* ws = (char*)d_ws;
    unsigned short* f1  = (unsigned short*)(ws);               // 104,857,600
    unsigned short* f2  = (unsigned short*)(ws + 104857600);   // 52,428,800
    unsigned short* f3  = (unsigned short*)(ws + 157286400);   // 26,214,400
    unsigned short* Wh1 = (unsigned short*)(ws + 183500800);
    unsigned short* Wl1 = (unsigned short*)(ws + 183762944);
    unsigned short* Wh2 = (unsigned short*)(ws + 184025088);
    unsigned short* Wl2 = (unsigned short*)(ws + 184287232);
    unsigned short* Wh3 = (unsigned short*)(ws + 184549376);
    unsigned short* Wl3 = (unsigned short*)(ws + 184614912);
    float* g      = (float*)(ws + 184680448);                  // 3,276,800
    float* counts = (float*)(ws + 187957248);                  // 512
    float* pooled = (float*)(ws + 187957760);                  // 65,536

    hipMemsetAsync(counts, 0, 512 + 65536, stream);

    wprep3<<<1152, 256, 0, stream>>>(w1, w2, w3, Wh1, Wl1, Wh2, Wl2, Wh3, Wl3);

    conv1_fused<<<3200, 256, 0, stream>>>(Wh1, Wl1, b1, feature, f1);
    conv_mfma<512, 2><<<1600, 256, 0, stream>>>(Wh2, Wl2, b2, f1, f2);
    conv_mfma<256, 1><<<800,  256, 0, stream>>>(Wh3, Wl3, b3, f2, f3);

    label_scatter<<<dim3(B_SZ, 10), 256, 0, stream>>>(lbl, g, counts);
    pool2<<<dim3(B_SZ, 8), 256, 0, stream>>>(f3, g, pooled);
    finalize<<<B_SZ, 256, 0, stream>>>(pooled, counts, out);
}

// Round 7
// 362.533 us; speedup vs baseline: 1.1155x; 1.1155x over previous
//
#include <hip/hip_runtime.h>

#define B_SZ   16
#define P_IN   6400
#define H_IN   80
#define OUTHW  160
#define NCLASS 8

typedef __attribute__((ext_vector_type(8))) short  short8v;
typedef __attribute__((ext_vector_type(4))) float  f32x4;
typedef __attribute__((ext_vector_type(4))) unsigned short ushort4v;

__device__ __forceinline__ unsigned short f2bf(float x) {
    union { float f; unsigned int u; } v; v.f = x;
    unsigned int r = v.u + 0x7fffu + ((v.u >> 16) & 1u);   // RNE
    return (unsigned short)(r >> 16);
}
__device__ __forceinline__ float bf2f(unsigned short h) {
    union { unsigned int u; float f; } v; v.u = ((unsigned int)h) << 16;
    return v.f;
}

__device__ __forceinline__ void gload16(const void* g, void* lds) {
    __builtin_amdgcn_global_load_lds(
        (const __attribute__((address_space(1))) unsigned int*)g,
        (__attribute__((address_space(3))) unsigned int*)lds, 16, 0, 0);
}

// ---------- fused weight prep: fp32 -> bf16 hi/lo ----------
__global__ void wprep3(const float* __restrict__ w1, const float* __restrict__ w2,
                       const float* __restrict__ w3,
                       unsigned short* __restrict__ h1, unsigned short* __restrict__ l1,
                       unsigned short* __restrict__ h2, unsigned short* __restrict__ l2,
                       unsigned short* __restrict__ h3, unsigned short* __restrict__ l3)
{
    int i = blockIdx.x * 256 + threadIdx.x;
    const float* src; unsigned short *h, *l; int off;
    if (i < 131072)      { src = w1; h = h1; l = l1; off = i; }
    else if (i < 262144) { src = w2; h = h2; l = l2; off = i - 131072; }
    else                 { src = w3; h = h3; l = l3; off = i - 262144;
                           if (off >= 32768) return; }
    float v = src[off];
    unsigned short hi = f2bf(v);
    h[off] = hi;
    l[off] = f2bf(v - bf2f(hi));
}

// ---------- conv1: fused f32-feature -> MFMA (conversion at STAGE time) ----------
// 128x128 tile, BK=32, NK=8, 4 waves 2x2, frag 4x4. A = Wh/Wl via gload_lds
// (slot swizzle, as proven). B = feature f32 reg-staged: 16 coalesced dword
// loads along n per thread -> f2bf in regs -> 2x ds_write_b128 into bf16
// [n][k] tile with slot s=(g+(n>>1)+(n>>3))&3 (write & read both balanced).
// Compute phase = pure vectorized b128 reads + MFMA (identical shape to conv2).
__global__ __launch_bounds__(256, 3)
void conv1_fused(const unsigned short* __restrict__ Wh, const unsigned short* __restrict__ Wl,
                 const float* __restrict__ bias,
                 const float* __restrict__ F,          // [b][256][6400] f32
                 unsigned short* __restrict__ Y)       // [b][6400][512] bf16
{
    constexpr int K = 256, NK = 8, NM = 4, M = 512;
    __shared__ unsigned short As_h[2][4096], As_l[2][4096], Bs[2][4096];
    const int tid = threadIdx.x, lane = tid & 63, w = tid >> 6;
    const int wm = w >> 1, wn = w & 1;

    const int nb = gridDim.x, id = blockIdx.x;
    const int wg = (id & 7) * (nb >> 3) + (id >> 3);
    const int bb  = wg / (50 * NM);
    const int rem = wg - bb * (50 * NM);
    const int n0 = (rem / NM) * 128;
    const int m0 = (rem % NM) * 128;

    const size_t abase = (size_t)m0 * K;

    // B loading: thread owns n = tid&127, k-half = tid>>7 (16 k-rows)
    const int bn  = tid & 127;
    const int bkh = tid >> 7;
    const float* Fb = F + (size_t)bb * K * P_IN + (size_t)(bkh * 16) * P_IN + n0 + bn;

    f32x4 acc[4][4];
#pragma unroll
    for (int i = 0; i < 4; ++i)
#pragma unroll
        for (int j = 0; j < 4; ++j) acc[i][j] = (f32x4)0.f;

    // A staging (gload_lds, 8 chunks of 1KB; wave w owns chunks 2w,2w+1)
    int a_row[2], a_k8[2], a_lo[2];
#pragma unroll
    for (int q = 0; q < 2; ++q) {
        const int ch = 2 * w + q;
        a_row[q] = ch * 16 + (lane >> 2);
        a_k8[q]  = ((((lane & 3) - (a_row[q] >> 1)) & 3) << 3);
        a_lo[q]  = ch * 512;
    }
    // B write offsets: chunk c = bkh*2+h holds k-group c; slot = (c + f(n)) & 3
    const int fbn = (bn >> 1) + (bn >> 3);
    int b_wo[2];
#pragma unroll
    for (int h = 0; h < 2; ++h) {
        const int c = bkh * 2 + h;
        b_wo[h] = bn * 32 + (((c + fbn) & 3) << 3);
    }
    // fragment read offsets
    const int gsel = lane >> 4;
    int off_a[4], off_b[4];
#pragma unroll
    for (int mi = 0; mi < 4; ++mi) {
        const int r = wm * 64 + mi * 16 + (lane & 15);
        off_a[mi] = r * 32 + (((gsel + (r >> 1)) & 3) << 3);
    }
#pragma unroll
    for (int ni = 0; ni < 4; ++ni) {
        const int r = wn * 64 + ni * 16 + (lane & 15);
        off_b[ni] = r * 32 + (((gsel + (r >> 1) + (r >> 3)) & 3) << 3);
    }

    float bld[16];

#define ISSUE_B(kt) do {                                                      \
    _Pragma("unroll")                                                         \
    for (int j = 0; j < 16; ++j)                                              \
        bld[j] = Fb[(size_t)((kt) * 32 + j) * P_IN];                          \
} while (0)

#define WRITE_B(buf) do {                                                     \
    _Pragma("unroll")                                                         \
    for (int h = 0; h < 2; ++h) {                                             \
        union { short8v v; unsigned short u[8]; } pk;                         \
        _Pragma("unroll")                                                     \
        for (int j = 0; j < 8; ++j) pk.u[j] = f2bf(bld[h * 8 + j]);           \
        *(short8v*)&Bs[buf][b_wo[h]] = pk.v;                                  \
    }                                                                         \
} while (0)

#define STAGE_A(buf, kt) do {                                                 \
    _Pragma("unroll")                                                         \
    for (int q = 0; q < 2; ++q) {                                             \
        const size_t gW = abase + (size_t)a_row[q] * K + (kt) * 32 + a_k8[q]; \
        gload16(Wh + gW, &As_h[buf][a_lo[q]]);                                \
        gload16(Wl + gW, &As_l[buf][a_lo[q]]);                                \
    }                                                                         \
} while (0)

    ISSUE_B(0);
    STAGE_A(0, 0);
    WRITE_B(0);            // compiler waits vmcnt(4): B regs ready, A in flight
    __syncthreads();       // drains A(0)

    int cur = 0;
    for (int t = 0; t < NK; ++t) {
        if (t + 1 < NK) { ISSUE_B(t + 1); STAGE_A(cur ^ 1, t + 1); }
        short8v ah[4], al[4], bv[4];
#pragma unroll
        for (int mi = 0; mi < 4; ++mi) {
            ah[mi] = *(const short8v*)&As_h[cur][off_a[mi]];
            al[mi] = *(const short8v*)&As_l[cur][off_a[mi]];
        }
#pragma unroll
        for (int ni = 0; ni < 4; ++ni)
            bv[ni] = *(const short8v*)&Bs[cur][off_b[ni]];
#pragma unroll
        for (int mi = 0; mi < 4; ++mi)
#pragma unroll
            for (int ni = 0; ni < 4; ++ni) {
                acc[mi][ni] = __builtin_amdgcn_mfma_f32_16x16x32_bf16(ah[mi], bv[ni], acc[mi][ni], 0, 0, 0);
                acc[mi][ni] = __builtin_amdgcn_mfma_f32_16x16x32_bf16(al[mi], bv[ni], acc[mi][ni], 0, 0, 0);
            }
        if (t + 1 < NK) {
            __builtin_amdgcn_sched_barrier(0);   // keep vmcnt-wait + writes BELOW the MFMAs
            WRITE_B(cur ^ 1);
        }
        __syncthreads();   // drains A(t+1) gloads + B writes; reads of cur done
        cur ^= 1;
    }
#undef ISSUE_B
#undef WRITE_B
#undef STAGE_A

    const int lhi = lane >> 4;
#pragma unroll
    for (int mi = 0; mi < 4; ++mi) {
        const int m_base = m0 + wm * 64 + mi * 16 + lhi * 4;
        const float4 b4 = *(const float4*)&bias[m_base];
#pragma unroll
        for (int ni = 0; ni < 4; ++ni) {
            const int n = n0 + wn * 64 + ni * 16 + (lane & 15);
            const size_t o = ((size_t)bb * P_IN + n) * M + m_base;
            ushort4v u;
            u.x = f2bf(fmaxf(acc[mi][ni][0] + b4.x, 0.f));
            u.y = f2bf(fmaxf(acc[mi][ni][1] + b4.y, 0.f));
            u.z = f2bf(fmaxf(acc[mi][ni][2] + b4.z, 0.f));
            u.w = f2bf(fmaxf(acc[mi][ni][3] + b4.w, 0.f));
            *(ushort4v*)&Y[o] = u;
        }
    }
}

// ---------- conv2/conv3: R3-proven structure (BK=64, single-buffer, 48KB) ----------
template<int K, int NM>
__global__ __launch_bounds__(256, 3)
void conv_mfma(const unsigned short* __restrict__ Wh, const unsigned short* __restrict__ Wl,
               const float* __restrict__ bias,
               const unsigned short* __restrict__ X, unsigned short* __restrict__ Y)
{
    constexpr int M = NM * 128;
    __shared__ unsigned short As_h[8192], As_l[8192], Bs[8192];
    const int tid = threadIdx.x, lane = tid & 63, w = tid >> 6;
    const int wm = w >> 1, wn = w & 1;

    const int nb = gridDim.x, id = blockIdx.x;
    const int wg = (id & 7) * (nb >> 3) + (id >> 3);
    const int bb  = wg / (50 * NM);
    const int rem = wg - bb * (50 * NM);
    const int n0 = (rem / NM) * 128;
    const int m0 = (rem % NM) * 128;

    const size_t xbase = ((size_t)bb * P_IN + n0) * K;

    f32x4 acc[4][4];
#pragma unroll
    for (int i = 0; i < 4; ++i)
#pragma unroll
        for (int j = 0; j < 4; ++j) acc[i][j] = (f32x4)0.f;

    const int srow = lane >> 3;
    const int scol = lane & 7;

    for (int k0 = 0; k0 < K; k0 += 64) {
#pragma unroll
        for (int q = 0; q < 4; ++q) {
            const int c   = w * 4 + q;
            const int row = c * 8 + srow;
            const int kc  = scol ^ (row & 7);
            const size_t ga = (size_t)(m0 + row) * K + k0 + kc * 8;
            const size_t gx = xbase + (size_t)row * K + k0 + kc * 8;
            const int lo = c * 512;
            gload16(Wh + ga, &As_h[lo]);
            gload16(Wl + ga, &As_l[lo]);
            gload16(X + gx, &Bs[lo]);
        }
        __syncthreads();
#pragma unroll
        for (int s = 0; s < 2; ++s) {
            short8v ah[4], al[4], bv[4];
            const int kc = s * 4 + (lane >> 4);
#pragma unroll
            for (int mi = 0; mi < 4; ++mi) {
                const int m = wm * 64 + mi * 16 + (lane & 15);
                const int off = m * 64 + ((kc ^ (m & 7)) << 3);
                ah[mi] = *(const short8v*)&As_h[off];
                al[mi] = *(const short8v*)&As_l[off];
            }
#pragma unroll
            for (int ni = 0; ni < 4; ++ni) {
                const int n = wn * 64 + ni * 16 + (lane & 15);
                const int off = n * 64 + ((kc ^ (n & 7)) << 3);
                bv[ni] = *(const short8v*)&Bs[off];
            }
#pragma unroll
            for (int mi = 0; mi < 4; ++mi)
#pragma unroll
                for (int ni = 0; ni < 4; ++ni) {
                    acc[mi][ni] = __builtin_amdgcn_mfma_f32_16x16x32_bf16(ah[mi], bv[ni], acc[mi][ni], 0, 0, 0);
                    acc[mi][ni] = __builtin_amdgcn_mfma_f32_16x16x32_bf16(al[mi], bv[ni], acc[mi][ni], 0, 0, 0);
                }
        }
        __syncthreads();
    }

    const int lhi = lane >> 4;
#pragma unroll
    for (int mi = 0; mi < 4; ++mi) {
        const int m_base = m0 + wm * 64 + mi * 16 + lhi * 4;
        const float4 b4 = *(const float4*)&bias[m_base];
#pragma unroll
        for (int ni = 0; ni < 4; ++ni) {
            const int n = n0 + wn * 64 + ni * 16 + (lane & 15);
            const size_t o = ((size_t)bb * P_IN + n) * M + m_base;
            ushort4v u;
            u.x = f2bf(fmaxf(acc[mi][ni][0] + b4.x, 0.f));
            u.y = f2bf(fmaxf(acc[mi][ni][1] + b4.y, 0.f));
            u.z = f2bf(fmaxf(acc[mi][ni][2] + b4.z, 0.f));
            u.w = f2bf(fmaxf(acc[mi][ni][3] + b4.w, 0.f));
            *(ushort4v*)&Y[o] = u;
        }
    }
}

// ---------- fused scatter + pool: g never touches global memory ----------
// Block (b, slab): slab owns in-rows [8*slab, 8*slab+8) (640 pixels). Phase 1:
// scatter bilinear label weights into LDS sg[8][640] (exact tap-ownership as
// before, verified). Phase 2: pooled[b][k][c] += sum_{p in slab} sg[k][p]*f3[b][p][c].
__global__ __launch_bounds__(256)
void scatter_pool(const int* __restrict__ lbl, const unsigned short* __restrict__ f3,
                  float* __restrict__ pooled, float* __restrict__ counts)
{
    __shared__ float sg[NCLASS][640];
    __shared__ float hist[NCLASS];
    const int b = blockIdx.x, slab = blockIdx.y;
    const int tid = threadIdx.x;
    const int r0 = slab * 8;
    for (int i = tid; i < NCLASS * 640; i += 256) ((float*)sg)[i] = 0.f;
    if (tid < NCLASS) hist[tid] = 0.f;
    __syncthreads();

    const int ibase = 2 * r0 - 1;
    for (int idx = tid; idx < 18 * 160; idx += 256) {
        const int ir = idx / 160, j = idx - ir * 160;
        const int i = ibase + ir;
        if (i < 0 || i >= OUTHW) continue;
        const int k = lbl[(size_t)b * (OUTHW * OUTHW) + i * OUTHW + j];
        const int mi = i >> 1, mj = j >> 1;
        int y0, y1, x0, x1; float wy0, wy1, wx0, wx1;
        if (i & 1) { y0 = mi; y1 = (mi < H_IN - 1) ? mi + 1 : H_IN - 1; wy0 = 0.75f; wy1 = 0.25f; }
        else       { y0 = (mi > 0) ? mi - 1 : 0; y1 = mi;               wy0 = 0.25f; wy1 = 0.75f; }
        if (j & 1) { x0 = mj; x1 = (mj < H_IN - 1) ? mj + 1 : H_IN - 1; wx0 = 0.75f; wx1 = 0.25f; }
        else       { x0 = (mj > 0) ? mj - 1 : 0; x1 = mj;               wx0 = 0.25f; wx1 = 0.75f; }
        if (mi >= r0 && mi < r0 + 8) atomicAdd(&hist[k], 1.f);
        const int ry0 = y0 - r0, ry1 = y1 - r0;
        if (ry0 >= 0 && ry0 < 8) {
            atomicAdd(&sg[k][ry0 * 80 + x0], wy0 * wx0);
            atomicAdd(&sg[k][ry0 * 80 + x1], wy0 * wx1);
        }
        if (ry1 >= 0 && ry1 < 8) {
            atomicAdd(&sg[k][ry1 * 80 + x0], wy1 * wx0);
            atomicAdd(&sg[k][ry1 * 80 + x1], wy1 * wx1);
        }
    }
    __syncthreads();

    // phase 2: pool over this slab's 640 pixels
    const int c  = tid & 127;
    const int kg = tid >> 7;   // 0..1 -> classes kg*4..+3
    float acc0 = 0.f, acc1 = 0.f, acc2 = 0.f, acc3 = 0.f;
    const unsigned short* fb = f3 + ((size_t)b * P_IN + r0 * 80) * 128 + c;
    for (int p = 0; p < 640; ++p) {
        const float fv = bf2f(fb[(size_t)p * 128]);
        acc0 = fmaf(fv, sg[kg * 4 + 0][p], acc0);
        acc1 = fmaf(fv, sg[kg * 4 + 1][p], acc1);
        acc2 = fmaf(fv, sg[kg * 4 + 2][p], acc2);
        acc3 = fmaf(fv, sg[kg * 4 + 3][p], acc3);
    }
    atomicAdd(&pooled[((size_t)b * NCLASS + kg * 4 + 0) * 128 + c], acc0);
    atomicAdd(&pooled[((size_t)b * NCLASS + kg * 4 + 1) * 128 + c], acc1);
    atomicAdd(&pooled[((size_t)b * NCLASS + kg * 4 + 2) * 128 + c], acc2);
    atomicAdd(&pooled[((size_t)b * NCLASS + kg * 4 + 3) * 128 + c], acc3);
    if (tid < NCLASS) atomicAdd(&counts[b * NCLASS + tid], hist[tid]);
}

__global__ void finalize(const float* __restrict__ pooled, const float* __restrict__ counts,
                         float* __restrict__ out)
{
    const int b = blockIdx.x;
#pragma unroll
    for (int i = threadIdx.x; i < NCLASS * 128; i += 256) {
        const int k = i >> 7;
        const float cnt = counts[b * NCLASS + k];
        out[(size_t)b * NCLASS * 128 + i] = pooled[(size_t)b * NCLASS * 128 + i] / (cnt + 1e-8f);
    }
    if (threadIdx.x < NCLASS)
        out[B_SZ * NCLASS * 128 + b * NCLASS + threadIdx.x] =
            (counts[b * NCLASS + threadIdx.x] > 0.f) ? 1.f : 0.f;
}

extern "C" void kernel_launch(void* const* d_in, const int* in_sizes, int n_in,
                              void* d_out, int out_size, void* d_ws, size_t ws_size,
                              hipStream_t stream)
{
    const float* feature = (const float*)d_in[0];
    const int*   lbl     = (const int*)d_in[1];
    const float* w1 = (const float*)d_in[2];
    const float* b1 = (const float*)d_in[3];
    const float* w2 = (const float*)d_in[4];
    const float* b2 = (const float*)d_in[5];
    const float* w3 = (const float*)d_in[6];
    const float* b3 = (const float*)d_in[7];
    float* out = (float*)d_out;

    char* ws = (char*)d_ws;
    unsigned short* f1  = (unsigned short*)(ws);               // 104,857,600
    unsigned short* f2  = (unsigned short*)(ws + 104857600);   // 52,428,800
    unsigned short* f3  = (unsigned short*)(ws + 157286400);   // 26,214,400
    unsigned short* Wh1 = (unsigned short*)(ws + 183500800);
    unsigned short* Wl1 = (unsigned short*)(ws + 183762944);
    unsigned short* Wh2 = (unsigned short*)(ws + 184025088);
    unsigned short* Wl2 = (unsigned short*)(ws + 184287232);
    unsigned short* Wh3 = (unsigned short*)(ws + 184549376);
    unsigned short* Wl3 = (unsigned short*)(ws + 184614912);
    float* counts = (float*)(ws + 184680448);                  // 512
    float* pooled = (float*)(ws + 184680960);                  // 65,536

    hipMemsetAsync(counts, 0, 512 + 65536, stream);

    wprep3<<<1152, 256, 0, stream>>>(w1, w2, w3, Wh1, Wl1, Wh2, Wl2, Wh3, Wl3);

    conv1_fused<<<3200, 256, 0, stream>>>(Wh1, Wl1, b1, feature, f1);
    conv_mfma<512, 2><<<1600, 256, 0, stream>>>(Wh2, Wl2, b2, f1, f2);
    conv_mfma<256, 1><<<800,  256, 0, stream>>>(Wh3, Wl3, b3, f2, f3);

    scatter_pool<<<dim3(B_SZ, 10), 256, 0, stream>>>(lbl, f3, pooled, counts);
    finalize<<<B_SZ, 256, 0, stream>>>(pooled, counts, out);
}